// Round 18
// baseline (45.930 us; speedup 1.0000x reference)
//
#include <hip/hip_runtime.h>
#include <hip/hip_bf16.h>
#include <hip/hip_fp16.h>
#include <stdint.h>

#define NB 2048
#define NU 512
#define NL 32
#define NH 64

typedef float    f4    __attribute__((ext_vector_type(4)));
typedef uint32_t u32x4 __attribute__((ext_vector_type(4)));
typedef _Float16 h8    __attribute__((ext_vector_type(8)));
typedef _Float16 h2    __attribute__((ext_vector_type(2)));
typedef __fp16   hv2   __attribute__((ext_vector_type(2)));   // cvt_pkrtz's native type

__device__ __forceinline__ f4 mfma16h(u32x4 a, u32x4 b, f4 c) {
    return __builtin_amdgcn_mfma_f32_16x16x32_f16(
        __builtin_bit_cast(h8, a), __builtin_bit_cast(h8, b), c, 0, 0, 0);
}

// RNE fp16 pair pack (staging / encoder, one-time per value)
__device__ __forceinline__ uint32_t pk2h(float a, float b) {
    uint32_t la = (uint32_t)__half_as_ushort(__float2half_rn(a));
    uint32_t hb = (uint32_t)__half_as_ushort(__float2half_rn(b));
    return la | (hb << 16);
}

// RTZ fp16 pack (activations, 1 VALU op)
__device__ __forceinline__ uint32_t pk_rtz(float e, float o) {
    hv2 v = __builtin_amdgcn_cvt_pkrtz(e, o);
    return __builtin_bit_cast(uint32_t, v);
}

// pack + relu, NO inline asm: cvt_pkrtz then elementwise max (emits
// v_pk_max_f16, scheduler-visible). r9-r16 used an asm block here; 32 asm
// blocks/iter = opaque scheduling objects. This round isolates that variable.
__device__ __forceinline__ uint32_t pk_relu(float e, float o) {
    hv2 v = __builtin_amdgcn_cvt_pkrtz(e, o);
    hv2 z = {(__fp16)0, (__fp16)0};
    v = __builtin_elementwise_max(v, z);
    return __builtin_bit_cast(uint32_t, v);
}

// packed fp16 dot2 with f32 accumulate
__device__ __forceinline__ float dot2(uint32_t a, uint32_t b, float c) {
    return __builtin_amdgcn_fdot2(__builtin_bit_cast(h2, a),
                                  __builtin_bit_cast(h2, b), c, false);
}

// butterfly sum over lane-bits 4,5 via permlane swaps (proven asm form;
// only 4 asm ops per double-iter, off the main layer chain).
__device__ __forceinline__ float red_lg(float x) {
    float a = x, b = x;
    asm("v_permlane16_swap_b32 %0, %1" : "+v"(a), "+v"(b));
    x = a + b;
    a = x; b = x;
    asm("v_permlane32_swap_b32 %0, %1" : "+v"(a), "+v"(b));
    return a + b;
}

// ---------------------------------------------------------------- encoder ---
// 256 blocks x 512 threads (2 waves/SIMD), 8 rows/block, 1 row/wave L1-L3.
__global__ __launch_bounds__(512)
void enc_kernel(const float* __restrict__ x,
                const float* __restrict__ We1, const float* __restrict__ be1,
                const float* __restrict__ We2, const float* __restrict__ be2,
                const float* __restrict__ We3, const float* __restrict__ be3,
                const float* __restrict__ We4, const float* __restrict__ be4,
                uint32_t* __restrict__ zpk)
{
    const int RE = 8;
    __shared__ float xs[RE][512];
    __shared__ float ws[128 * 64];
    __shared__ float h[RE][NH];
    __shared__ float h2s[RE][NH];

    const int t  = threadIdx.x;
    const int r0 = blockIdx.x * RE;

    {
        const f4* xv  = (const f4*)(x + (size_t)r0 * 512);
        f4*       xsv = (f4*)&xs[0][0];
        for (int i = t; i < RE * 512 / 4; i += 512) xsv[i] = xv[i];
    }

    const int j = t & 63;
    const int w = t >> 6;          // wave 0..7 = row

    float acc0 = be1[j];
    for (int kc = 0; kc < 512; kc += 128) {
        __syncthreads();
        const f4* wv  = (const f4*)(We1 + (size_t)kc * 64);
        f4*       wsv = (f4*)ws;
        for (int i = t; i < 128 * 64 / 4; i += 512) wsv[i] = wv[i];
        __syncthreads();
        #pragma unroll 8
        for (int k = 0; k < 128; ++k)
            acc0 = fmaf(xs[w][kc + k], ws[k * 64 + j], acc0);
    }
    acc0 = fmaxf(acc0, 0.f);
    __syncthreads();
    h[w][j] = acc0;
    __syncthreads();

    acc0 = be2[j];
    #pragma unroll
    for (int k = 0; k < 64; ++k)
        acc0 = fmaf(h[w][k], We2[k * 64 + j], acc0);
    acc0 = fmaxf(acc0, 0.f);
    h2s[w][j] = acc0;
    __syncthreads();

    acc0 = be3[j];
    #pragma unroll
    for (int k = 0; k < 64; ++k)
        acc0 = fmaf(h2s[w][k], We3[k * 64 + j], acc0);
    acc0 = fmaxf(acc0, 0.f);
    h[w][j] = acc0;
    __syncthreads();

    if (t < 256) {
        const int j4  = t & 31;
        const int row = t >> 5;    // 0..7
        float acc = be4[j4];
        #pragma unroll
        for (int k = 0; k < 64; ++k)
            acc = fmaf(h[row][k], We4[k * 32 + j4], acc);
        float nb = __shfl_xor(acc, 1);
        if ((j4 & 1) == 0)
            zpk[(size_t)(r0 + row) * 16 + (j4 >> 1)] = pk2h(acc, nb);
    }
}

// ---------------------------------------------------------------- decoder ---
// r16 structure, pk_relu asm-free (this round's single variable).
// 512 blocks (1/unit), 4 waves x 2 row-streams x 16 rows, 16 double-iters.
// 16x16x32 MFMA, exchange-free permuted features, resident bias C-quads,
// permlane L4 reduce. LDS padded to 54.9 KB -> 2 blocks/CU -> RA budget 256.
template <int K2>
__device__ __forceinline__ void stageW(const float* __restrict__ g,
                                       uint32_t (*dst)[68], int t)
{
    for (int g4 = t; g4 < K2 * 16; g4 += 256) {
        const int k2 = g4 >> 4, c4 = (g4 & 15) << 2;
        f4 a = *(const f4*)(g + (size_t)(2 * k2) * NH + c4);
        f4 b = *(const f4*)(g + (size_t)(2 * k2 + 1) * NH + c4);
        u32x4 p;
        p[0] = pk2h(a[0], b[0]);
        p[1] = pk2h(a[1], b[1]);
        p[2] = pk2h(a[2], b[2]);
        p[3] = pk2h(a[3], b[3]);
        *(u32x4*)&dst[k2][c4] = p;
    }
}

__global__ __launch_bounds__(256)
void dec_kernel(const uint32_t* __restrict__ zpk,
                const float* __restrict__ Wd1, const float* __restrict__ bd1,
                const float* __restrict__ Wd2, const float* __restrict__ bd2,
                const float* __restrict__ Wd3, const float* __restrict__ bd3,
                const float* __restrict__ Wd4, const float* __restrict__ bd4,
                float* __restrict__ out)
{
    __shared__ uint32_t wpk1[16][68];    // fp16-pair packed W^T
    __shared__ uint32_t wpk2[32][68];
    __shared__ uint32_t wpk3[150][68];   // rows 32..149 = occupancy pad
    __shared__ float bsh[3][NH];
    __shared__ float w4s[NH];

    const int bid = blockIdx.x;
    // bijective unit swizzle: 16 consecutive u (one 64B out-line) share bid%8 -> one XCD
    const int u = ((bid & 7) << 4) | (((bid >> 3) & 3) << 7) | (bid >> 5);
    const int t = threadIdx.x;

    stageW<16>(Wd1 + (size_t)u * NL * NH, wpk1, t);
    stageW<32>(Wd2 + (size_t)u * NH * NH, wpk2, t);
    stageW<32>(Wd3 + (size_t)u * NH * NH, wpk3, t);
    if (t < NH) {
        bsh[0][t] = bd1[(size_t)u * NH + t];
        bsh[1][t] = bd2[(size_t)u * NH + t];
        bsh[2][t] = bd3[(size_t)u * NH + t];
        w4s[t]    = Wd4[(size_t)u * NH + t];
    }
    __syncthreads();

    const int w  = t >> 6;          // wave 0..3
    const int lr = t & 15;          // batch-row lane
    const int lg = (t & 63) >> 4;   // lane group 0..3
    const float b4 = bd4[u];

    // permuted out-feature for (tile mt, tile-row lr)
    int cperm[4];
    #pragma unroll
    for (int mt = 0; mt < 4; ++mt)
        cperm[mt] = ((mt >> 1) << 5) + ((lr >> 2) << 3) + ((mt & 1) << 2) + (lr & 3);

    // ---- register A-fragments (W^T), permuted columns ----
    u32x4 a1[4], a2[4][2], a3[4][2];
    #pragma unroll
    for (int mt = 0; mt < 4; ++mt) {
        const int c = cperm[mt];
        #pragma unroll
        for (int i = 0; i < 4; ++i)
            a1[mt][i] = wpk1[lg * 4 + i][c];
        #pragma unroll
        for (int ks = 0; ks < 2; ++ks) {
            #pragma unroll
            for (int i = 0; i < 4; ++i) {
                a2[mt][ks][i] = wpk2[ks * 16 + lg * 4 + i][c];
                a3[mt][ks][i] = wpk3[ks * 16 + lg * 4 + i][c];
            }
        }
    }

    // lane's held feature-quad base for tile mt
    int bq[4];
    #pragma unroll
    for (int mt = 0; mt < 4; ++mt)
        bq[mt] = ((mt >> 1) << 5) + (lg << 3) + ((mt & 1) << 2);

    // loop-invariant bias C-quads (resident)
    f4 bc1[4], bc2[4], bc3[4];
    #pragma unroll
    for (int mt = 0; mt < 4; ++mt) {
        bc1[mt] = *(const f4*)&bsh[0][bq[mt]];
        bc2[mt] = *(const f4*)&bsh[1][bq[mt]];
        bc3[mt] = *(const f4*)&bsh[2][bq[mt]];
    }

    // packed wd4 at permuted positions
    uint32_t wd4pk[4][2];
    #pragma unroll
    for (int mt = 0; mt < 4; ++mt) {
        wd4pk[mt][0] = pk2h(w4s[bq[mt]],     w4s[bq[mt] + 1]);
        wd4pk[mt][1] = pk2h(w4s[bq[mt] + 2], w4s[bq[mt] + 3]);
    }

    const int rl = w * 16 + lr;     // block-local row (stream base)

    u32x4 zc[2];
    zc[0] = *(const u32x4*)(zpk + (size_t)rl * 16 + lg * 4);
    zc[1] = *(const u32x4*)(zpk + (size_t)(64 + rl) * 16 + lg * 4);

    for (int it = 0; it < 16; ++it) {
        const int rb  = it * 128 + rl;
        const int rbn = ((it + 1) & 15) * 128 + rl;
        u32x4 zn[2];
        zn[0] = *(const u32x4*)(zpk + (size_t)rbn * 16 + lg * 4);
        zn[1] = *(const u32x4*)(zpk + (size_t)(rbn + 64) * 16 + lg * 4);

        f4 acc[2][4];

        // ---- L1 (both streams) ----
        #pragma unroll
        for (int s = 0; s < 2; ++s)
            #pragma unroll
            for (int mt = 0; mt < 4; ++mt)
                acc[s][mt] = mfma16h(a1[mt], zc[s], bc1[mt]);

        // ---- h1 B-frags: lane-local pack, no exchange ----
        u32x4 bf0[2], bf1[2];
        #pragma unroll
        for (int s = 0; s < 2; ++s) {
            bf0[s][0] = pk_relu(acc[s][0][0], acc[s][0][1]);
            bf0[s][1] = pk_relu(acc[s][0][2], acc[s][0][3]);
            bf0[s][2] = pk_relu(acc[s][1][0], acc[s][1][1]);
            bf0[s][3] = pk_relu(acc[s][1][2], acc[s][1][3]);
            bf1[s][0] = pk_relu(acc[s][2][0], acc[s][2][1]);
            bf1[s][1] = pk_relu(acc[s][2][2], acc[s][2][3]);
            bf1[s][2] = pk_relu(acc[s][3][0], acc[s][3][1]);
            bf1[s][3] = pk_relu(acc[s][3][2], acc[s][3][3]);
        }

        // ---- L2 ----
        #pragma unroll
        for (int s = 0; s < 2; ++s)
            #pragma unroll
            for (int mt = 0; mt < 4; ++mt)
                acc[s][mt] = mfma16h(a2[mt][0], bf0[s], bc2[mt]);
        #pragma unroll
        for (int s = 0; s < 2; ++s)
            #pragma unroll
            for (int mt = 0; mt < 4; ++mt)
                acc[s][mt] = mfma16h(a2[mt][1], bf1[s], acc[s][mt]);

        // ---- h2 B-frags ----
        #pragma unroll
        for (int s = 0; s < 2; ++s) {
            bf0[s][0] = pk_relu(acc[s][0][0], acc[s][0][1]);
            bf0[s][1] = pk_relu(acc[s][0][2], acc[s][0][3]);
            bf0[s][2] = pk_relu(acc[s][1][0], acc[s][1][1]);
            bf0[s][3] = pk_relu(acc[s][1][2], acc[s][1][3]);
            bf1[s][0] = pk_relu(acc[s][2][0], acc[s][2][1]);
            bf1[s][1] = pk_relu(acc[s][2][2], acc[s][2][3]);
            bf1[s][2] = pk_relu(acc[s][3][0], acc[s][3][1]);
            bf1[s][3] = pk_relu(acc[s][3][2], acc[s][3][3]);
        }

        // ---- L3 ----
        #pragma unroll
        for (int s = 0; s < 2; ++s)
            #pragma unroll
            for (int mt = 0; mt < 4; ++mt)
                acc[s][mt] = mfma16h(a3[mt][0], bf0[s], bc3[mt]);
        #pragma unroll
        for (int s = 0; s < 2; ++s)
            #pragma unroll
            for (int mt = 0; mt < 4; ++mt)
                acc[s][mt] = mfma16h(a3[mt][1], bf1[s], acc[s][mt]);

        // ---- L4: pack-relu h3 + dot2 + permlane reduce ----
        #pragma unroll
        for (int s = 0; s < 2; ++s) {
            float pa = 0.f, pb = 0.f;
            #pragma unroll
            for (int mt = 0; mt < 4; ++mt) {
                uint32_t p0 = pk_relu(acc[s][mt][0], acc[s][mt][1]);
                uint32_t p1 = pk_relu(acc[s][mt][2], acc[s][mt][3]);
                pa = dot2(p0, wd4pk[mt][0], pa);
                pb = dot2(p1, wd4pk[mt][1], pb);
            }
            float part = red_lg(pa + pb);
            if ((t & 48) == 0)
                out[(size_t)(rb + s * 64) * NU + u] = part + b4;
        }

        zc[0] = zn[0]; zc[1] = zn[1];
    }
}

// ----------------------------------------------------------------- launch ---
extern "C" void kernel_launch(void* const* d_in, const int* in_sizes, int n_in,
                              void* d_out, int out_size, void* d_ws, size_t ws_size,
                              hipStream_t stream)
{
    const float* x   = (const float*)d_in[0];
    const float* We1 = (const float*)d_in[1];
    const float* be1 = (const float*)d_in[2];
    const float* We2 = (const float*)d_in[3];
    const float* be2 = (const float*)d_in[4];
    const float* We3 = (const float*)d_in[5];
    const float* be3 = (const float*)d_in[6];
    const float* We4 = (const float*)d_in[7];
    const float* be4 = (const float*)d_in[8];
    const float* Wd1 = (const float*)d_in[9];
    const float* bd1 = (const float*)d_in[10];
    const float* Wd2 = (const float*)d_in[11];
    const float* bd2 = (const float*)d_in[12];
    const float* Wd3 = (const float*)d_in[13];
    const float* bd3 = (const float*)d_in[14];
    const float* Wd4 = (const float*)d_in[15];
    const float* bd4 = (const float*)d_in[16];
    float* out = (float*)d_out;

    uint32_t* zpk = (uint32_t*)d_ws;   // 128 KB packed-fp16 z

    enc_kernel<<<NB / 8, 512, 0, stream>>>(x, We1, be1, We2, be2, We3, be3,
                                           We4, be4, zpk);
    dec_kernel<<<NU, 256, 0, stream>>>(zpk, Wd1, bd1, Wd2, bd2,
                                       Wd3, bd3, Wd4, bd4, out);
}

// Round 21
// 44.314 us; speedup vs baseline: 1.0365x; 1.0365x over previous
//
#include <hip/hip_runtime.h>
#include <hip/hip_bf16.h>
#include <hip/hip_fp16.h>
#include <stdint.h>

#define NB 2048
#define NU 512
#define NL 32
#define NH 64

typedef float    f4    __attribute__((ext_vector_type(4)));
typedef uint32_t u32x4 __attribute__((ext_vector_type(4)));
typedef _Float16 h8    __attribute__((ext_vector_type(8)));
typedef _Float16 h2    __attribute__((ext_vector_type(2)));

__device__ __forceinline__ f4 mfma16h(u32x4 a, u32x4 b, f4 c) {
    return __builtin_amdgcn_mfma_f32_16x16x32_f16(
        __builtin_bit_cast(h8, a), __builtin_bit_cast(h8, b), c, 0, 0, 0);
}

// RNE fp16 pair pack (staging / encoder, one-time per value)
__device__ __forceinline__ uint32_t pk2h(float a, float b) {
    uint32_t la = (uint32_t)__half_as_ushort(__float2half_rn(a));
    uint32_t hb = (uint32_t)__half_as_ushort(__float2half_rn(b));
    return la | (hb << 16);
}

// RTZ fp16 pack (activations, 1 VALU op)
__device__ __forceinline__ uint32_t pk_rtz(float e, float o) {
    return __builtin_bit_cast(uint32_t, __builtin_amdgcn_cvt_pkrtz(e, o));
}

// pack + relu in 2 ops (identical to fmax-then-cvt)
__device__ __forceinline__ uint32_t pk_relu(float e, float o) {
    uint32_t r = pk_rtz(e, o);
    asm("v_pk_max_f16 %0, %1, 0" : "=v"(r) : "v"(r));
    return r;
}

// packed fp16 dot2 with f32 accumulate
__device__ __forceinline__ float dot2(uint32_t a, uint32_t b, float c) {
    return __builtin_amdgcn_fdot2(__builtin_bit_cast(h2, a),
                                  __builtin_bit_cast(h2, b), c, false);
}

// butterfly sum over lane-bits 4 and 5 via permlane swaps (VALU only, no DS).
// Same add association as the shfl_xor pair -> bit-identical (r14 verified).
__device__ __forceinline__ float red_lg(float x) {
    float a = x, b = x;
    asm("v_permlane16_swap_b32 %0, %1" : "+v"(a), "+v"(b));
    x = a + b;
    a = x; b = x;
    asm("v_permlane32_swap_b32 %0, %1" : "+v"(a), "+v"(b));
    return a + b;
}

// ---------------------------------------------------------------- encoder ---
// 256 blocks x 512 threads (2 waves/SIMD), 8 rows/block, 1 row/wave L1-L3.
__global__ __launch_bounds__(512)
void enc_kernel(const float* __restrict__ x,
                const float* __restrict__ We1, const float* __restrict__ be1,
                const float* __restrict__ We2, const float* __restrict__ be2,
                const float* __restrict__ We3, const float* __restrict__ be3,
                const float* __restrict__ We4, const float* __restrict__ be4,
                uint32_t* __restrict__ zpk)
{
    const int RE = 8;
    __shared__ float xs[RE][512];
    __shared__ float ws[128 * 64];
    __shared__ float h[RE][NH];
    __shared__ float h2s[RE][NH];

    const int t  = threadIdx.x;
    const int r0 = blockIdx.x * RE;

    {
        const f4* xv  = (const f4*)(x + (size_t)r0 * 512);
        f4*       xsv = (f4*)&xs[0][0];
        for (int i = t; i < RE * 512 / 4; i += 512) xsv[i] = xv[i];
    }

    const int j = t & 63;
    const int w = t >> 6;          // wave 0..7 = row

    float acc0 = be1[j];
    for (int kc = 0; kc < 512; kc += 128) {
        __syncthreads();
        const f4* wv  = (const f4*)(We1 + (size_t)kc * 64);
        f4*       wsv = (f4*)ws;
        for (int i = t; i < 128 * 64 / 4; i += 512) wsv[i] = wv[i];
        __syncthreads();
        #pragma unroll 8
        for (int k = 0; k < 128; ++k)
            acc0 = fmaf(xs[w][kc + k], ws[k * 64 + j], acc0);
    }
    acc0 = fmaxf(acc0, 0.f);
    __syncthreads();
    h[w][j] = acc0;
    __syncthreads();

    acc0 = be2[j];
    #pragma unroll
    for (int k = 0; k < 64; ++k)
        acc0 = fmaf(h[w][k], We2[k * 64 + j], acc0);
    acc0 = fmaxf(acc0, 0.f);
    h2s[w][j] = acc0;
    __syncthreads();

    acc0 = be3[j];
    #pragma unroll
    for (int k = 0; k < 64; ++k)
        acc0 = fmaf(h2s[w][k], We3[k * 64 + j], acc0);
    acc0 = fmaxf(acc0, 0.f);
    h[w][j] = acc0;
    __syncthreads();

    if (t < 256) {
        const int j4  = t & 31;
        const int row = t >> 5;    // 0..7
        float acc = be4[j4];
        #pragma unroll
        for (int k = 0; k < 64; ++k)
            acc = fmaf(h[row][k], We4[k * 32 + j4], acc);
        float nb = __shfl_xor(acc, 1);
        if ((j4 & 1) == 0)
            zpk[(size_t)(r0 + row) * 16 + (j4 >> 1)] = pk2h(acc, nb);
    }
}

// ---------------------------------------------------------------- decoder ---
// FINAL (r14 config, best passing: 44.86 us total). 512 blocks (1/unit),
// 4 waves x FOUR row-streams x 16 rows, 8 macro-iters. 16x16x32 builtin MFMA
// (r19/r20: raw-asm MFMA is incorrect without compiler MAI-hazard handling),
// exchange-free permuted features, permlane reduce, biases via LDS broadcast.
// LDS padded to 54.9 KB -> 2 blocks/CU -> RA budget 256 (allocator law).
// Residual ~4x above MFMA-pipe floor is the per-layer MFMA->VALU boundary
// hazard cost, intrinsic to the fused structure (r9-r18 ablations).
template <int K2>
__device__ __forceinline__ void stageW(const float* __restrict__ g,
                                       uint32_t (*dst)[68], int t)
{
    for (int g4 = t; g4 < K2 * 16; g4 += 256) {
        const int k2 = g4 >> 4, c4 = (g4 & 15) << 2;
        f4 a = *(const f4*)(g + (size_t)(2 * k2) * NH + c4);
        f4 b = *(const f4*)(g + (size_t)(2 * k2 + 1) * NH + c4);
        u32x4 p;
        p[0] = pk2h(a[0], b[0]);
        p[1] = pk2h(a[1], b[1]);
        p[2] = pk2h(a[2], b[2]);
        p[3] = pk2h(a[3], b[3]);
        *(u32x4*)&dst[k2][c4] = p;
    }
}

__global__ __launch_bounds__(256)
void dec_kernel(const uint32_t* __restrict__ zpk,
                const float* __restrict__ Wd1, const float* __restrict__ bd1,
                const float* __restrict__ Wd2, const float* __restrict__ bd2,
                const float* __restrict__ Wd3, const float* __restrict__ bd3,
                const float* __restrict__ Wd4, const float* __restrict__ bd4,
                float* __restrict__ out)
{
    __shared__ uint32_t wpk1[16][68];    // fp16-pair packed W^T
    __shared__ uint32_t wpk2[32][68];
    __shared__ uint32_t wpk3[150][68];   // rows 32..149 = occupancy pad
    __shared__ float bsh[3][NH];
    __shared__ float w4s[NH];

    const int bid = blockIdx.x;
    // bijective unit swizzle: 16 consecutive u (one 64B out-line) share bid%8 -> one XCD
    const int u = ((bid & 7) << 4) | (((bid >> 3) & 3) << 7) | (bid >> 5);
    const int t = threadIdx.x;

    stageW<16>(Wd1 + (size_t)u * NL * NH, wpk1, t);
    stageW<32>(Wd2 + (size_t)u * NH * NH, wpk2, t);
    stageW<32>(Wd3 + (size_t)u * NH * NH, wpk3, t);
    if (t < NH) {
        bsh[0][t] = bd1[(size_t)u * NH + t];
        bsh[1][t] = bd2[(size_t)u * NH + t];
        bsh[2][t] = bd3[(size_t)u * NH + t];
        w4s[t]    = Wd4[(size_t)u * NH + t];
    }
    __syncthreads();

    const int w  = t >> 6;          // wave 0..3
    const int lr = t & 15;          // batch-row lane
    const int lg = (t & 63) >> 4;   // lane group 0..3
    const float b4 = bd4[u];

    // permuted out-feature for (tile mt, tile-row lr)
    int cperm[4];
    #pragma unroll
    for (int mt = 0; mt < 4; ++mt)
        cperm[mt] = ((mt >> 1) << 5) + ((lr >> 2) << 3) + ((mt & 1) << 2) + (lr & 3);

    // ---- register A-fragments (W^T), permuted columns ----
    u32x4 a1[4], a2[4][2], a3[4][2];
    #pragma unroll
    for (int mt = 0; mt < 4; ++mt) {
        const int c = cperm[mt];
        #pragma unroll
        for (int i = 0; i < 4; ++i)
            a1[mt][i] = wpk1[lg * 4 + i][c];
        #pragma unroll
        for (int ks = 0; ks < 2; ++ks) {
            #pragma unroll
            for (int i = 0; i < 4; ++i) {
                a2[mt][ks][i] = wpk2[ks * 16 + lg * 4 + i][c];
                a3[mt][ks][i] = wpk3[ks * 16 + lg * 4 + i][c];
            }
        }
    }

    // lane's held feature-quad base for tile mt
    int bq[4];
    #pragma unroll
    for (int mt = 0; mt < 4; ++mt)
        bq[mt] = ((mt >> 1) << 5) + (lg << 3) + ((mt & 1) << 2);

    // packed wd4 (8 resident regs)
    uint32_t wd4pk[4][2];
    #pragma unroll
    for (int mt = 0; mt < 4; ++mt) {
        wd4pk[mt][0] = pk2h(w4s[bq[mt]],     w4s[bq[mt] + 1]);
        wd4pk[mt][1] = pk2h(w4s[bq[mt] + 2], w4s[bq[mt] + 3]);
    }

    const int rl = w * 16 + lr;     // block-local row (stream base)

    u32x4 zc[4];
    #pragma unroll
    for (int s = 0; s < 4; ++s)
        zc[s] = *(const u32x4*)(zpk + (size_t)(rl + s * 64) * 16 + lg * 4);

    for (int it = 0; it < 8; ++it) {
        const int rb  = it * 256 + rl;
        const int rbn = ((it + 1) & 7) * 256 + rl;

        f4 acc[4][4];

        // ---- L1 (all 4 streams; bias via LDS broadcast) ----
        {
            f4 c0 = *(const f4*)&bsh[0][bq[0]];
            f4 c1 = *(const f4*)&bsh[0][bq[1]];
            f4 c2 = *(const f4*)&bsh[0][bq[2]];
            f4 c3 = *(const f4*)&bsh[0][bq[3]];
            #pragma unroll
            for (int s = 0; s < 4; ++s) {
                acc[s][0] = mfma16h(a1[0], zc[s], c0);
                acc[s][1] = mfma16h(a1[1], zc[s], c1);
                acc[s][2] = mfma16h(a1[2], zc[s], c2);
                acc[s][3] = mfma16h(a1[3], zc[s], c3);
            }
        }

        // prefetch next iter's z (zc consumed above)
        u32x4 zn[4];
        #pragma unroll
        for (int s = 0; s < 4; ++s)
            zn[s] = *(const u32x4*)(zpk + (size_t)(rbn + s * 64) * 16 + lg * 4);

        // ---- L2 + L3 per stream (bf liveness local; streams independent) ----
        f4 bc2[4], bc3[4];
        #pragma unroll
        for (int mt = 0; mt < 4; ++mt) {
            bc2[mt] = *(const f4*)&bsh[1][bq[mt]];
            bc3[mt] = *(const f4*)&bsh[2][bq[mt]];
        }
        #pragma unroll
        for (int s = 0; s < 4; ++s) {
            u32x4 bf0, bf1;
            bf0[0] = pk_relu(acc[s][0][0], acc[s][0][1]);
            bf0[1] = pk_relu(acc[s][0][2], acc[s][0][3]);
            bf0[2] = pk_relu(acc[s][1][0], acc[s][1][1]);
            bf0[3] = pk_relu(acc[s][1][2], acc[s][1][3]);
            bf1[0] = pk_relu(acc[s][2][0], acc[s][2][1]);
            bf1[1] = pk_relu(acc[s][2][2], acc[s][2][3]);
            bf1[2] = pk_relu(acc[s][3][0], acc[s][3][1]);
            bf1[3] = pk_relu(acc[s][3][2], acc[s][3][3]);

            #pragma unroll
            for (int mt = 0; mt < 4; ++mt)
                acc[s][mt] = mfma16h(a2[mt][0], bf0, bc2[mt]);
            #pragma unroll
            for (int mt = 0; mt < 4; ++mt)
                acc[s][mt] = mfma16h(a2[mt][1], bf1, acc[s][mt]);

            bf0[0] = pk_relu(acc[s][0][0], acc[s][0][1]);
            bf0[1] = pk_relu(acc[s][0][2], acc[s][0][3]);
            bf0[2] = pk_relu(acc[s][1][0], acc[s][1][1]);
            bf0[3] = pk_relu(acc[s][1][2], acc[s][1][3]);
            bf1[0] = pk_relu(acc[s][2][0], acc[s][2][1]);
            bf1[1] = pk_relu(acc[s][2][2], acc[s][2][3]);
            bf1[2] = pk_relu(acc[s][3][0], acc[s][3][1]);
            bf1[3] = pk_relu(acc[s][3][2], acc[s][3][3]);

            #pragma unroll
            for (int mt = 0; mt < 4; ++mt)
                acc[s][mt] = mfma16h(a3[mt][0], bf0, bc3[mt]);
            #pragma unroll
            for (int mt = 0; mt < 4; ++mt)
                acc[s][mt] = mfma16h(a3[mt][1], bf1, acc[s][mt]);
        }

        // ---- L4: pack-relu h3 + dot2 + permlane reduce (no DS) ----
        #pragma unroll
        for (int s = 0; s < 4; ++s) {
            float pa = 0.f, pb = 0.f;
            #pragma unroll
            for (int mt = 0; mt < 4; ++mt) {
                uint32_t p0 = pk_relu(acc[s][mt][0], acc[s][mt][1]);
                uint32_t p1 = pk_relu(acc[s][mt][2], acc[s][mt][3]);
                pa = dot2(p0, wd4pk[mt][0], pa);
                pb = dot2(p1, wd4pk[mt][1], pb);
            }
            float part = red_lg(pa + pb);
            if ((t & 48) == 0)
                out[(size_t)(rb + s * 64) * NU + u] = part + b4;
        }

        #pragma unroll
        for (int s = 0; s < 4; ++s) zc[s] = zn[s];
    }
}

// ----------------------------------------------------------------- launch ---
extern "C" void kernel_launch(void* const* d_in, const int* in_sizes, int n_in,
                              void* d_out, int out_size, void* d_ws, size_t ws_size,
                              hipStream_t stream)
{
    const float* x   = (const float*)d_in[0];
    const float* We1 = (const float*)d_in[1];
    const float* be1 = (const float*)d_in[2];
    const float* We2 = (const float*)d_in[3];
    const float* be2 = (const float*)d_in[4];
    const float* We3 = (const float*)d_in[5];
    const float* be3 = (const float*)d_in[6];
    const float* We4 = (const float*)d_in[7];
    const float* be4 = (const float*)d_in[8];
    const float* Wd1 = (const float*)d_in[9];
    const float* bd1 = (const float*)d_in[10];
    const float* Wd2 = (const float*)d_in[11];
    const float* bd2 = (const float*)d_in[12];
    const float* Wd3 = (const float*)d_in[13];
    const float* bd3 = (const float*)d_in[14];
    const float* Wd4 = (const float*)d_in[15];
    const float* bd4 = (const float*)d_in[16];
    float* out = (float*)d_out;

    uint32_t* zpk = (uint32_t*)d_ws;   // 128 KB packed-fp16 z

    enc_kernel<<<NB / 8, 512, 0, stream>>>(x, We1, be1, We2, be2, We3, be3,
                                           We4, be4, zpk);
    dec_kernel<<<NU, 256, 0, stream>>>(zpk, Wd1, bd1, Wd2, bd2,
                                       Wd3, bd3, Wd4, bd4, out);
}